// Round 5
// baseline (436.311 us; speedup 1.0000x reference)
//
#include <hip/hip_runtime.h>
#include <hip/hip_bf16.h>

#define B_  128
#define J_  4096
#define D_  64
#define H_  128
#define E_  256
#define Z_  32

typedef __attribute__((ext_vector_type(8))) short short8;    // 8 bf16 (4 VGPRs)
typedef __attribute__((ext_vector_type(4))) float floatx4;   // MFMA C/D

// workspace layout (bytes)
#define OFF_G      0u          // G' fp32 [4096][128] = 2 MiB
#define OFF_GSTATS 2097152u    // float4 per j        = 64 KiB
#define OFF_SCAL   2162688u    // {mean(w0), mean(w0^2)}
#define OFF_W0C    2162944u    // fp32[128]
#define OFF_C3     2163456u    // fp32[128] (= hbt1)
#define OFF_W2F    2163968u    // uint4[16][64] bf16 B-frags = 16 KiB
#define OFF_POOL   2180352u    // fp32[128][64] = 32 KiB
#define OFF_CNT    2213120u    // fp32[128]
#define OFF_TICK   2213632u    // int[32] tickets

// 1-instr RNE pack on gfx950; library fallback. low16 = bf16(a), high16 = bf16(b).
#if defined(__has_builtin)
#if __has_builtin(__builtin_amdgcn_cvt_pk_bf16_f32)
#define HAVE_CVT_PK_BF16 1
#endif
#endif

#ifdef HAVE_CVT_PK_BF16
typedef __attribute__((ext_vector_type(2))) __bf16 bf16x2;
static __device__ __forceinline__ unsigned pk2(float a, float b) {
    return __builtin_bit_cast(unsigned, __builtin_amdgcn_cvt_pk_bf16_f32(a, b));
}
#else
static __device__ __forceinline__ unsigned pk2(float a, float b) {
    __hip_bfloat162 t = __float22bfloat162_rn(make_float2(a, b));
    union { __hip_bfloat162 h; unsigned u; } c; c.h = t; return c.u;
}
#endif

// ---------------------------------------------------------------------------
// pre_kernel (4106 blocks x 128): fuses G-build + prep + accumulator zeroing.
//  bid < 4096 : G'[j,h], Gstats[j] for j = bid
//  bid == 4096: scal, w0c, c3, W2 bf16 B-frag pack
//  bid > 4096 : zero pooled/cnt/tickets (9 blocks x 4 KiB)
// ---------------------------------------------------------------------------
__global__ __launch_bounds__(128) void pre_kernel(
    const float* __restrict__ F, const float* __restrict__ hW1,
    const float* __restrict__ hb1, const float* __restrict__ hg1,
    const float* __restrict__ hbt1, const float* __restrict__ hW2,
    float* __restrict__ Gp, float4* __restrict__ Gstats,
    float* __restrict__ scal, float* __restrict__ w0c, float* __restrict__ c3,
    uint4* __restrict__ w2f, float4* __restrict__ zero4)
{
    __shared__ float red[6];
    const int bid = blockIdx.x;
    const int t = threadIdx.x;

    if (bid >= 4097) {                       // zero 9 * 4 KiB: pooled+cnt+tickets
        const int base = (bid - 4097) * 256;
        zero4[base + t]       = make_float4(0.f, 0.f, 0.f, 0.f);
        zero4[base + 128 + t] = make_float4(0.f, 0.f, 0.f, 0.f);
        return;
    }

    if (bid == 4096) {                       // prep
        const float w0h = hW1[t];
        float s = w0h, q = w0h * w0h;
#pragma unroll
        for (int off = 32; off; off >>= 1) {
            s += __shfl_xor(s, off);
            q += __shfl_xor(q, off);
        }
        if ((t & 63) == 0) { red[(t >> 6) * 2] = s; red[(t >> 6) * 2 + 1] = q; }
        __syncthreads();
        const float mw0  = (red[0] + red[2]) * (1.f / (float)H_);
        const float ew02 = (red[1] + red[3]) * (1.f / (float)H_);
        if (t == 0) { scal[0] = mw0; scal[1] = ew02; }
        w0c[t] = (hW1[t] - mw0) * hg1[t];
        c3[t]  = hbt1[t];

        const int lane = t & 63, half = t >> 6;
        const int quad = lane >> 4, col = lane & 15;
        for (int f = half; f < 16; f += 2) {
            const int kstep = f >> 2, nt = f & 3;
            const int kbase = kstep * 32 + quad * 8;
            const int n = nt * 16 + col;
            unsigned r[4];
#pragma unroll
            for (int p = 0; p < 4; p++)
                r[p] = pk2(hW2[(kbase + 2*p) * D_ + n], hW2[(kbase + 2*p + 1) * D_ + n]);
            w2f[f * 64 + lane] = make_uint4(r[0], r[1], r[2], r[3]);
        }
        return;
    }

    // ---- G part: j = bid ----
    const int j = bid;
    const int h = t;
    const float* frow = F + (size_t)j * D_;
    float a0 = hb1[h], a1 = 0.f, a2 = 0.f, a3 = 0.f;
#pragma unroll
    for (int d = 0; d < D_; d += 4) {
        a0 = fmaf(frow[d + 0], hW1[(d + 1) * H_ + h], a0);
        a1 = fmaf(frow[d + 1], hW1[(d + 2) * H_ + h], a1);
        a2 = fmaf(frow[d + 2], hW1[(d + 3) * H_ + h], a2);
        a3 = fmaf(frow[d + 3], hW1[(d + 4) * H_ + h], a3);
    }
    const float acc = (a0 + a1) + (a2 + a3);

    const float w0h = hW1[h];
    float s1 = acc, s2 = w0h * acc, s3 = acc * acc;
#pragma unroll
    for (int off = 32; off; off >>= 1) {
        s1 += __shfl_xor(s1, off);
        s2 += __shfl_xor(s2, off);
        s3 += __shfl_xor(s3, off);
    }
    if ((h & 63) == 0) {
        int w = h >> 6;
        red[w*3+0] = s1; red[w*3+1] = s2; red[w*3+2] = s3;
    }
    __syncthreads();
    const float inv = 1.f / (float)H_;
    const float mG = (red[0] + red[3]) * inv;
    if (h == 0)
        Gstats[j] = make_float4(mG, (red[1]+red[4])*inv, (red[2]+red[5])*inv, 0.f);
    Gp[j * H_ + h] = (acc - mG) * hg1[h];
}

// ---------------------------------------------------------------------------
// main_kernel: round-3 proven hot loop + cnt accumulation + ticketed tail
// that runs the per-b head (3rd dispatch eliminated).
// ---------------------------------------------------------------------------
#define TPW 2
#define BB  4

__global__ __launch_bounds__(256, 4) void main_kernel(
    const float* __restrict__ x, const int* __restrict__ mask,
    const float* __restrict__ Gp, const float4* __restrict__ Gstats,
    const float* __restrict__ scal,
    const float* __restrict__ w0c, const float* __restrict__ c3,
    const uint4* __restrict__ w2f,
    const float* __restrict__ hb2, const float* __restrict__ hg2,
    const float* __restrict__ hbt2,
    const float* __restrict__ eW1, const float* __restrict__ eb1,
    const float* __restrict__ eW2, const float* __restrict__ eb2,
    float* __restrict__ pooled, float* __restrict__ cnt,
    int* __restrict__ tickets, float* __restrict__ out)
{
    __shared__ float c_lds[D_];
    __shared__ float e_lds[E_];
    __shared__ float hred[8];
    __shared__ int   tick_s;

    const int tid  = threadIdx.x;
    const int lane = tid & 63;
    const int wv   = tid >> 6;
    const int quad = lane >> 4;
    const int col  = lane & 15;
    const int b0   = blockIdx.y * BB;

    // ---- per-wave preload ----
    short8 w2r[16];
#pragma unroll
    for (int f = 0; f < 16; f++) {
        union { uint4 v; short8 s; } c; c.v = w2f[f * 64 + lane];
        w2r[f] = c.s;
    }
    float4 wc[4][2], cc[4][2];
#pragma unroll
    for (int k = 0; k < 4; k++) {
        wc[k][0] = ((const float4*)(w0c + k*32 + quad*8))[0];
        wc[k][1] = ((const float4*)(w0c + k*32 + quad*8))[1];
        cc[k][0] = ((const float4*)(c3  + k*32 + quad*8))[0];
        cc[k][1] = ((const float4*)(c3  + k*32 + quad*8))[1];
    }
    float hb2v[4], g2v[4], bt2v[4];
#pragma unroll
    for (int nt = 0; nt < 4; nt++) {
        hb2v[nt] = hb2[nt*16 + col];
        g2v[nt]  = hg2[nt*16 + col];
        bt2v[nt] = hbt2[nt*16 + col];
    }
    const float mw0s  = scal[0];
    const float ew02s = scal[1];

    float pool[BB][4], cna[BB];
#pragma unroll
    for (int bb = 0; bb < BB; bb++) {
        cna[bb] = 0.f;
#pragma unroll
        for (int nt = 0; nt < 4; nt++) pool[bb][nt] = 0.f;
    }

    for (int t = 0; t < TPW; t++) {
        const int tIdx = (blockIdx.x * 4 + wv) * TPW + t;
        const int j0   = tIdx * 16;
        const int rowA = j0 + col;

        // ---- tile loads (shared across BB batch rows) ----
        const float4 gs = Gstats[rowA];
        float xv[BB]; int4 mk[BB];
#pragma unroll
        for (int bb = 0; bb < BB; bb++) {
            xv[bb] = x[(size_t)(b0 + bb) * J_ + rowA];
            mk[bb] = *(const int4*)(mask + (size_t)(b0 + bb) * J_ + j0 + quad * 4);
        }
        const float* gpr = Gp + rowA * H_ + quad * 8;
        float4 ga[4][2];
#pragma unroll
        for (int k = 0; k < 4; k++) {
            ga[k][0] = ((const float4*)(gpr + k*32))[0];
            ga[k][1] = ((const float4*)(gpr + k*32))[1];
        }

#pragma unroll
        for (int bb = 0; bb < BB; bb++) {
            const float xA = xv[bb];
            const float mean = fmaf(xA, mw0s, gs.x);
            const float eh2  = fmaf(xA, fmaf(xA, ew02s, 2.f * gs.y), gs.z);
            const float r1   = rsqrtf(fmaf(-mean, mean, eh2) + 1e-5f);

            floatx4 acc[4];
#pragma unroll
            for (int nt = 0; nt < 4; nt++) acc[nt] = (floatx4){0.f, 0.f, 0.f, 0.f};

#pragma unroll
            for (int k = 0; k < 4; k++) {
                const float h0 = fmaxf(0.f, fmaf(fmaf(xA, wc[k][0].x, ga[k][0].x), r1, cc[k][0].x));
                const float h1 = fmaxf(0.f, fmaf(fmaf(xA, wc[k][0].y, ga[k][0].y), r1, cc[k][0].y));
                const float h2 = fmaxf(0.f, fmaf(fmaf(xA, wc[k][0].z, ga[k][0].z), r1, cc[k][0].z));
                const float h3 = fmaxf(0.f, fmaf(fmaf(xA, wc[k][0].w, ga[k][0].w), r1, cc[k][0].w));
                const float h4 = fmaxf(0.f, fmaf(fmaf(xA, wc[k][1].x, ga[k][1].x), r1, cc[k][1].x));
                const float h5 = fmaxf(0.f, fmaf(fmaf(xA, wc[k][1].y, ga[k][1].y), r1, cc[k][1].y));
                const float h6 = fmaxf(0.f, fmaf(fmaf(xA, wc[k][1].z, ga[k][1].z), r1, cc[k][1].z));
                const float h7 = fmaxf(0.f, fmaf(fmaf(xA, wc[k][1].w, ga[k][1].w), r1, cc[k][1].w));
                union { unsigned u[4]; short8 s; } af;
                af.u[0] = pk2(h0, h1);
                af.u[1] = pk2(h2, h3);
                af.u[2] = pk2(h4, h5);
                af.u[3] = pk2(h6, h7);
                acc[0] = __builtin_amdgcn_mfma_f32_16x16x32_bf16(af.s, w2r[k*4+0], acc[0], 0, 0, 0);
                acc[1] = __builtin_amdgcn_mfma_f32_16x16x32_bf16(af.s, w2r[k*4+1], acc[1], 0, 0, 0);
                acc[2] = __builtin_amdgcn_mfma_f32_16x16x32_bf16(af.s, w2r[k*4+2], acc[2], 0, 0, 0);
                acc[3] = __builtin_amdgcn_mfma_f32_16x16x32_bf16(af.s, w2r[k*4+3], acc[3], 0, 0, 0);
            }

            // ---- epilogue: bias, LN2 over d=64, relu, masked pool ----
            float sa[4], qa[4];
#pragma unroll
            for (int r = 0; r < 4; r++) {
                const float v0 = acc[0][r] + hb2v[0];
                const float v1 = acc[1][r] + hb2v[1];
                const float v2 = acc[2][r] + hb2v[2];
                const float v3 = acc[3][r] + hb2v[3];
                acc[0][r] = v0; acc[1][r] = v1; acc[2][r] = v2; acc[3][r] = v3;
                sa[r] = (v0 + v1) + (v2 + v3);
                qa[r] = fmaf(v0, v0, fmaf(v1, v1, fmaf(v2, v2, v3 * v3)));
            }
#pragma unroll
            for (int m = 1; m < 16; m <<= 1) {
#pragma unroll
                for (int r = 0; r < 4; r++) {
                    sa[r] += __shfl_xor(sa[r], m);
                    qa[r] += __shfl_xor(qa[r], m);
                }
            }
            float mrr[4];
            mrr[0] = (mk[bb].x > 0) ? 1.f : 0.f;
            mrr[1] = (mk[bb].y > 0) ? 1.f : 0.f;
            mrr[2] = (mk[bb].z > 0) ? 1.f : 0.f;
            mrr[3] = (mk[bb].w > 0) ? 1.f : 0.f;
#pragma unroll
            for (int r = 0; r < 4; r++) {
                const float m2 = sa[r] * (1.f / 64.f);
                const float v2 = fmaf(-m2, m2, qa[r] * (1.f / 64.f));
                const float r2 = rsqrtf(v2 + 1e-5f);
#pragma unroll
                for (int nt = 0; nt < 4; nt++) {
                    const float rg  = r2 * g2v[nt];
                    const float off = fmaf(-m2, rg, bt2v[nt]);
                    const float o   = fmaxf(0.f, fmaf(acc[nt][r], rg, off));
                    pool[bb][nt] = fmaf(mrr[r], o, pool[bb][nt]);
                }
            }
            cna[bb] += (mrr[0] + mrr[1]) + (mrr[2] + mrr[3]);
        }
    }

    // reduce pools/counts over the 4 quad-groups and write
#pragma unroll
    for (int m = 16; m < 64; m <<= 1) {
#pragma unroll
        for (int bb = 0; bb < BB; bb++) {
#pragma unroll
            for (int nt = 0; nt < 4; nt++)
                pool[bb][nt] += __shfl_xor(pool[bb][nt], m);
            cna[bb] += __shfl_xor(cna[bb], m);
        }
    }
    if (lane < 16) {
#pragma unroll
        for (int bb = 0; bb < BB; bb++) {
#pragma unroll
            for (int nt = 0; nt < 4; nt++)
                atomicAdd(&pooled[(size_t)(b0 + bb) * D_ + nt * 16 + lane], pool[bb][nt]);
            if (lane == 0) atomicAdd(&cnt[b0 + bb], cna[bb]);
        }
    }

    // ---- ticketed tail: last block of this b-group runs the per-b head ----
    __threadfence();
    __syncthreads();
    if (tid == 0) tick_s = atomicAdd(&tickets[blockIdx.y], 1);
    __syncthreads();
    if (tick_s != 31) return;
    __threadfence();

    const int t256 = tid;
    const int wid = tid >> 6;
    for (int bb = 0; bb < BB; bb++) {
        const int b = b0 + bb;
        // atomic reads: guaranteed-coherent cross-XCD view of pooled/cnt
        if (t256 == 0) c_lds[0] = fmaxf(atomicAdd(&cnt[b], 0.f), 1.f);
        __syncthreads();
        const float cn = c_lds[0];
        __syncthreads();
        if (t256 < D_) c_lds[t256] = atomicAdd(&pooled[(size_t)b * D_ + t256], 0.f) / cn;
        __syncthreads();

        // layer 1: 64 -> 256
        float acc = eb1[t256];
#pragma unroll
        for (int d = 0; d < D_; d++)
            acc = fmaf(c_lds[d], eW1[(size_t)d * E_ + t256], acc);

        float s = acc, s2 = acc * acc;
#pragma unroll
        for (int off = 32; off; off >>= 1) {
            s  += __shfl_xor(s, off);
            s2 += __shfl_xor(s2, off);
        }
        if ((t256 & 63) == 0) { hred[wid * 2] = s; hred[wid * 2 + 1] = s2; }
        __syncthreads();
        s  = hred[0] + hred[2] + hred[4] + hred[6];
        s2 = hred[1] + hred[3] + hred[5] + hred[7];
        const float m = s * (1.f / (float)E_);
        const float v = fmaf(-m, m, s2 * (1.f / (float)E_));
        const float r = rsqrtf(v + 1e-5f);
        e_lds[t256] = fmaxf(0.f, (acc - m) * r);
        __syncthreads();

        // layer 2: 256 -> 64, first wave only
        if (t256 < 64) {
            float a2 = eb2[t256];
#pragma unroll 8
            for (int k = 0; k < E_; k++)
                a2 = fmaf(e_lds[k], eW2[(size_t)k * 64 + t256], a2);

            float u = a2, u2 = a2 * a2;
#pragma unroll
            for (int off = 32; off; off >>= 1) {
                u  += __shfl_xor(u, off);
                u2 += __shfl_xor(u2, off);
            }
            const float m2 = u * (1.f / 64.f);
            const float v2 = fmaf(-m2, m2, u2 * (1.f / 64.f));
            const float r2 = rsqrtf(v2 + 1e-5f);
            const float o  = fmaxf(0.f, (a2 - m2) * r2);
            if (t256 < Z_) out[(size_t)b * Z_ + t256] = o;
            else           out[(size_t)B_ * Z_ + (size_t)b * Z_ + (t256 - Z_)] = o;
        }
        __syncthreads();
    }
}

// ---------------------------------------------------------------------------
extern "C" void kernel_launch(void* const* d_in, const int* in_sizes, int n_in,
                              void* d_out, int out_size, void* d_ws, size_t ws_size,
                              hipStream_t stream) {
    const float* x    = (const float*)d_in[0];
    const int*   mask = (const int*)d_in[1];
    const float* F    = (const float*)d_in[2];
    const float* hW1  = (const float*)d_in[3];
    const float* hb1  = (const float*)d_in[4];
    const float* hg1  = (const float*)d_in[5];
    const float* hbt1 = (const float*)d_in[6];
    const float* hW2  = (const float*)d_in[7];
    const float* hb2  = (const float*)d_in[8];
    const float* hg2  = (const float*)d_in[9];
    const float* hbt2 = (const float*)d_in[10];
    const float* eW1  = (const float*)d_in[11];
    const float* eb1  = (const float*)d_in[12];
    const float* eW2  = (const float*)d_in[13];
    const float* eb2  = (const float*)d_in[14];
    float* out = (float*)d_out;

    char* ws = (char*)d_ws;
    float*  Gp     = (float*)(ws + OFF_G);
    float4* Gstats = (float4*)(ws + OFF_GSTATS);
    float*  scal   = (float*)(ws + OFF_SCAL);
    float*  w0c    = (float*)(ws + OFF_W0C);
    float*  c3     = (float*)(ws + OFF_C3);
    uint4*  w2f    = (uint4*)(ws + OFF_W2F);
    float*  pooled = (float*)(ws + OFF_POOL);
    float*  cnt    = (float*)(ws + OFF_CNT);
    int*    tick   = (int*)(ws + OFF_TICK);

    pre_kernel<<<J_ + 10, 128, 0, stream>>>(F, hW1, hb1, hg1, hbt1, hW2,
                                            Gp, Gstats, scal, w0c, c3, w2f,
                                            (float4*)pooled);
    main_kernel<<<dim3(J_ / (16 * 4 * TPW), B_ / BB), 256, 0, stream>>>(
        x, mask, Gp, Gstats, scal, w0c, c3, w2f, hb2, hg2, hbt2,
        eW1, eb1, eW2, eb2, pooled, cnt, tick, out);
}

// Round 6
// 138.005 us; speedup vs baseline: 3.1616x; 3.1616x over previous
//
#include <hip/hip_runtime.h>
#include <hip/hip_bf16.h>

#define B_  128
#define J_  4096
#define D_  64
#define H_  128
#define E_  256
#define Z_  32

typedef __attribute__((ext_vector_type(8))) short short8;    // 8 bf16 (4 VGPRs)
typedef __attribute__((ext_vector_type(4))) float floatx4;   // MFMA C/D

// workspace layout (bytes)
#define OFF_G      0u          // G' fp32 [4096][128] = 2 MiB
#define OFF_GSTATS 2097152u    // float4 per j        = 64 KiB
#define OFF_SCAL   2162688u    // {mean(w0), mean(w0^2)}
#define OFF_W0C    2162944u    // fp32[128]
#define OFF_C3     2163456u    // fp32[128] (= hbt1)
#define OFF_W2F    2163968u    // uint4[16][64] bf16 B-frags = 16 KiB
#define OFF_POOL   2180352u    // fp32[128][64] = 32 KiB

// 1-instr RNE pack on gfx950; library fallback. low16 = bf16(a), high16 = bf16(b).
#if defined(__has_builtin)
#if __has_builtin(__builtin_amdgcn_cvt_pk_bf16_f32)
#define HAVE_CVT_PK_BF16 1
#endif
#endif

#ifdef HAVE_CVT_PK_BF16
static __device__ __forceinline__ unsigned pk2(float a, float b) {
    return __builtin_bit_cast(unsigned, __builtin_amdgcn_cvt_pk_bf16_f32(a, b));
}
#else
static __device__ __forceinline__ unsigned pk2(float a, float b) {
    __hip_bfloat162 t = __float22bfloat162_rn(make_float2(a, b));
    union { __hip_bfloat162 h; unsigned u; } c; c.h = t; return c.u;
}
#endif

// ---------------------------------------------------------------------------
// pre_kernel (1033 blocks x 128): fuses G-build + prep + pooled zeroing.
//  bid < 1024 : G'[j,h], Gstats[j] for j = bid*4 .. bid*4+3
//               (each hW1 column load feeds 4 FMAs -> 4x fewer loads)
//  bid == 1024: scal, w0c, c3, W2 bf16 B-frag pack
//  bid > 1024 : zero pooled (8 blocks x 4 KiB)
// ---------------------------------------------------------------------------
__global__ __launch_bounds__(128) void pre_kernel(
    const float* __restrict__ F, const float* __restrict__ hW1,
    const float* __restrict__ hb1, const float* __restrict__ hg1,
    const float* __restrict__ hbt1, const float* __restrict__ hW2,
    float* __restrict__ Gp, float4* __restrict__ Gstats,
    float* __restrict__ scal, float* __restrict__ w0c, float* __restrict__ c3,
    uint4* __restrict__ w2f, float4* __restrict__ zero4)
{
    __shared__ float red[24];
    const int bid = blockIdx.x;
    const int t = threadIdx.x;

    if (bid > 1024) {                        // zero pooled: 8 blocks x 4 KiB
        const int base = (bid - 1025) * 256;
        zero4[base + t]       = make_float4(0.f, 0.f, 0.f, 0.f);
        zero4[base + 128 + t] = make_float4(0.f, 0.f, 0.f, 0.f);
        return;
    }

    if (bid == 1024) {                       // prep
        const float w0h = hW1[t];
        float s = w0h, q = w0h * w0h;
#pragma unroll
        for (int off = 32; off; off >>= 1) {
            s += __shfl_xor(s, off);
            q += __shfl_xor(q, off);
        }
        if ((t & 63) == 0) { red[(t >> 6) * 2] = s; red[(t >> 6) * 2 + 1] = q; }
        __syncthreads();
        const float mw0  = (red[0] + red[2]) * (1.f / (float)H_);
        const float ew02 = (red[1] + red[3]) * (1.f / (float)H_);
        if (t == 0) { scal[0] = mw0; scal[1] = ew02; }
        w0c[t] = (hW1[t] - mw0) * hg1[t];
        c3[t]  = hbt1[t];

        const int lane = t & 63, half = t >> 6;
        const int quad = lane >> 4, col = lane & 15;
        for (int f = half; f < 16; f += 2) {
            const int kstep = f >> 2, nt = f & 3;
            const int kbase = kstep * 32 + quad * 8;
            const int n = nt * 16 + col;
            unsigned r[4];
#pragma unroll
            for (int p = 0; p < 4; p++)
                r[p] = pk2(hW2[(kbase + 2*p) * D_ + n], hW2[(kbase + 2*p + 1) * D_ + n]);
            w2f[f * 64 + lane] = make_uint4(r[0], r[1], r[2], r[3]);
        }
        return;
    }

    // ---- G part: j = bid*4 .. bid*4+3 ----
    const int j0 = bid * 4;
    const int h  = t;
    const float* f0 = F + (size_t)(j0 + 0) * D_;
    const float* f1 = F + (size_t)(j0 + 1) * D_;
    const float* f2p = F + (size_t)(j0 + 2) * D_;
    const float* f3 = F + (size_t)(j0 + 3) * D_;
    const float bias = hb1[h];
    float a0 = bias, a1 = bias, a2 = bias, a3 = bias;
#pragma unroll
    for (int d = 0; d < D_; d++) {
        const float w = hW1[(d + 1) * H_ + h];
        a0 = fmaf(f0[d], w, a0);
        a1 = fmaf(f1[d], w, a1);
        a2 = fmaf(f2p[d], w, a2);
        a3 = fmaf(f3[d], w, a3);
    }

    const float w0h = hW1[h];
    const float g1h = hg1[h];
    float accs[4] = {a0, a1, a2, a3};
#pragma unroll
    for (int q = 0; q < 4; q++) {
        float s1 = accs[q], s2 = w0h * accs[q], s3 = accs[q] * accs[q];
#pragma unroll
        for (int off = 32; off; off >>= 1) {
            s1 += __shfl_xor(s1, off);
            s2 += __shfl_xor(s2, off);
            s3 += __shfl_xor(s3, off);
        }
        if ((h & 63) == 0) {
            int w = h >> 6;
            red[q*6 + w*3 + 0] = s1; red[q*6 + w*3 + 1] = s2; red[q*6 + w*3 + 2] = s3;
        }
    }
    __syncthreads();
    const float inv = 1.f / (float)H_;
#pragma unroll
    for (int q = 0; q < 4; q++) {
        const float mG = (red[q*6 + 0] + red[q*6 + 3]) * inv;
        if (h == 0)
            Gstats[j0 + q] = make_float4(mG, (red[q*6+1] + red[q*6+4]) * inv,
                                             (red[q*6+2] + red[q*6+5]) * inv, 0.f);
        Gp[(j0 + q) * H_ + h] = (accs[q] - mG) * g1h;
    }
}

// ---------------------------------------------------------------------------
// main_kernel: round-3 proven hot loop (byte-identical structure; only the
// bf16 pack is the 1-instr v_cvt_pk_bf16_f32). DO NOT tighten launch_bounds:
// (256,2) -> 128 VGPR budget is exactly what this body needs; (256,4) spills
// the w2r/wc/cc working set to scratch (round-5: 750 MB HBM traffic, 9x slower).
// ---------------------------------------------------------------------------
#define TPW 2
#define BB  4

__global__ __launch_bounds__(256, 2) void main_kernel(
    const float* __restrict__ x, const int* __restrict__ mask,
    const float* __restrict__ Gp, const float4* __restrict__ Gstats,
    const float* __restrict__ scal,
    const float* __restrict__ w0c, const float* __restrict__ c3,
    const uint4* __restrict__ w2f,
    const float* __restrict__ hb2, const float* __restrict__ hg2,
    const float* __restrict__ hbt2,
    float* __restrict__ pooled)
{
    const int tid  = threadIdx.x;
    const int lane = tid & 63;
    const int wv   = tid >> 6;
    const int quad = lane >> 4;
    const int col  = lane & 15;
    const int b0   = blockIdx.y * BB;

    // ---- per-wave preload ----
    short8 w2r[16];
#pragma unroll
    for (int f = 0; f < 16; f++) {
        union { uint4 v; short8 s; } c; c.v = w2f[f * 64 + lane];
        w2r[f] = c.s;
    }
    float4 wc[4][2], cc[4][2];
#pragma unroll
    for (int k = 0; k < 4; k++) {
        wc[k][0] = ((const float4*)(w0c + k*32 + quad*8))[0];
        wc[k][1] = ((const float4*)(w0c + k*32 + quad*8))[1];
        cc[k][0] = ((const float4*)(c3  + k*32 + quad*8))[0];
        cc[k][1] = ((const float4*)(c3  + k*32 + quad*8))[1];
    }
    float hb2v[4], g2v[4], bt2v[4];
#pragma unroll
    for (int nt = 0; nt < 4; nt++) {
        hb2v[nt] = hb2[nt*16 + col];
        g2v[nt]  = hg2[nt*16 + col];
        bt2v[nt] = hbt2[nt*16 + col];
    }
    const float mw0s  = scal[0];
    const float ew02s = scal[1];

    float pool[BB][4];
#pragma unroll
    for (int bb = 0; bb < BB; bb++)
#pragma unroll
        for (int nt = 0; nt < 4; nt++) pool[bb][nt] = 0.f;

    for (int t = 0; t < TPW; t++) {
        const int tIdx = (blockIdx.x * 4 + wv) * TPW + t;
        const int j0   = tIdx * 16;
        const int rowA = j0 + col;

        // ---- tile loads (shared across BB batch rows) ----
        const float4 gs = Gstats[rowA];
        float xv[BB]; int4 mk[BB];
#pragma unroll
        for (int bb = 0; bb < BB; bb++) {
            xv[bb] = x[(size_t)(b0 + bb) * J_ + rowA];
            mk[bb] = *(const int4*)(mask + (size_t)(b0 + bb) * J_ + j0 + quad * 4);
        }
        const float* gpr = Gp + rowA * H_ + quad * 8;
        float4 ga[4][2];
#pragma unroll
        for (int k = 0; k < 4; k++) {
            ga[k][0] = ((const float4*)(gpr + k*32))[0];
            ga[k][1] = ((const float4*)(gpr + k*32))[1];
        }

#pragma unroll
        for (int bb = 0; bb < BB; bb++) {
            const float xA = xv[bb];
            const float mean = fmaf(xA, mw0s, gs.x);
            const float eh2  = fmaf(xA, fmaf(xA, ew02s, 2.f * gs.y), gs.z);
            const float r1   = rsqrtf(fmaf(-mean, mean, eh2) + 1e-5f);

            floatx4 acc[4];
#pragma unroll
            for (int nt = 0; nt < 4; nt++) acc[nt] = (floatx4){0.f, 0.f, 0.f, 0.f};

#pragma unroll
            for (int k = 0; k < 4; k++) {
                const float h0 = fmaxf(0.f, fmaf(fmaf(xA, wc[k][0].x, ga[k][0].x), r1, cc[k][0].x));
                const float h1 = fmaxf(0.f, fmaf(fmaf(xA, wc[k][0].y, ga[k][0].y), r1, cc[k][0].y));
                const float h2 = fmaxf(0.f, fmaf(fmaf(xA, wc[k][0].z, ga[k][0].z), r1, cc[k][0].z));
                const float h3 = fmaxf(0.f, fmaf(fmaf(xA, wc[k][0].w, ga[k][0].w), r1, cc[k][0].w));
                const float h4 = fmaxf(0.f, fmaf(fmaf(xA, wc[k][1].x, ga[k][1].x), r1, cc[k][1].x));
                const float h5 = fmaxf(0.f, fmaf(fmaf(xA, wc[k][1].y, ga[k][1].y), r1, cc[k][1].y));
                const float h6 = fmaxf(0.f, fmaf(fmaf(xA, wc[k][1].z, ga[k][1].z), r1, cc[k][1].z));
                const float h7 = fmaxf(0.f, fmaf(fmaf(xA, wc[k][1].w, ga[k][1].w), r1, cc[k][1].w));
                union { unsigned u[4]; short8 s; } af;
                af.u[0] = pk2(h0, h1);
                af.u[1] = pk2(h2, h3);
                af.u[2] = pk2(h4, h5);
                af.u[3] = pk2(h6, h7);
                acc[0] = __builtin_amdgcn_mfma_f32_16x16x32_bf16(af.s, w2r[k*4+0], acc[0], 0, 0, 0);
                acc[1] = __builtin_amdgcn_mfma_f32_16x16x32_bf16(af.s, w2r[k*4+1], acc[1], 0, 0, 0);
                acc[2] = __builtin_amdgcn_mfma_f32_16x16x32_bf16(af.s, w2r[k*4+2], acc[2], 0, 0, 0);
                acc[3] = __builtin_amdgcn_mfma_f32_16x16x32_bf16(af.s, w2r[k*4+3], acc[3], 0, 0, 0);
            }

            // ---- epilogue: bias, LN2 over d=64, relu, masked pool ----
            float sa[4], qa[4];
#pragma unroll
            for (int r = 0; r < 4; r++) {
                const float v0 = acc[0][r] + hb2v[0];
                const float v1 = acc[1][r] + hb2v[1];
                const float v2 = acc[2][r] + hb2v[2];
                const float v3 = acc[3][r] + hb2v[3];
                acc[0][r] = v0; acc[1][r] = v1; acc[2][r] = v2; acc[3][r] = v3;
                sa[r] = (v0 + v1) + (v2 + v3);
                qa[r] = fmaf(v0, v0, fmaf(v1, v1, fmaf(v2, v2, v3 * v3)));
            }
#pragma unroll
            for (int m = 1; m < 16; m <<= 1) {
#pragma unroll
                for (int r = 0; r < 4; r++) {
                    sa[r] += __shfl_xor(sa[r], m);
                    qa[r] += __shfl_xor(qa[r], m);
                }
            }
            float mrr[4];
            mrr[0] = (mk[bb].x > 0) ? 1.f : 0.f;
            mrr[1] = (mk[bb].y > 0) ? 1.f : 0.f;
            mrr[2] = (mk[bb].z > 0) ? 1.f : 0.f;
            mrr[3] = (mk[bb].w > 0) ? 1.f : 0.f;
#pragma unroll
            for (int r = 0; r < 4; r++) {
                const float m2 = sa[r] * (1.f / 64.f);
                const float v2 = fmaf(-m2, m2, qa[r] * (1.f / 64.f));
                const float r2 = rsqrtf(v2 + 1e-5f);
#pragma unroll
                for (int nt = 0; nt < 4; nt++) {
                    const float rg  = r2 * g2v[nt];
                    const float off = fmaf(-m2, rg, bt2v[nt]);
                    const float o   = fmaxf(0.f, fmaf(acc[nt][r], rg, off));
                    pool[bb][nt] = fmaf(mrr[r], o, pool[bb][nt]);
                }
            }
        }
    }

    // reduce pools over the 4 quad-groups and write
#pragma unroll
    for (int m = 16; m < 64; m <<= 1)
#pragma unroll
        for (int bb = 0; bb < BB; bb++)
#pragma unroll
            for (int nt = 0; nt < 4; nt++)
                pool[bb][nt] += __shfl_xor(pool[bb][nt], m);

    if (lane < 16) {
#pragma unroll
        for (int bb = 0; bb < BB; bb++)
#pragma unroll
            for (int nt = 0; nt < 4; nt++)
                atomicAdd(&pooled[(size_t)(b0 + bb) * D_ + nt * 16 + lane], pool[bb][nt]);
    }
}

// ---------------------------------------------------------------------------
// final_kernel: per-b head; computes cnt[b] from the mask row (coalesced).
// ---------------------------------------------------------------------------
__global__ __launch_bounds__(256) void final_kernel(
    const float* __restrict__ pooled, const int* __restrict__ mask,
    const float* __restrict__ eW1, const float* __restrict__ eb1,
    const float* __restrict__ eW2, const float* __restrict__ eb2,
    float* __restrict__ out)
{
    __shared__ float c_lds[D_];
    __shared__ float e_lds[E_];
    __shared__ float red[8];
    __shared__ float redc[4];
    const int b = blockIdx.x;
    const int t = threadIdx.x;
    const int lane = t & 63, wid = t >> 6;

    // count observed entries in this row (coalesced int4 reads)
    {
        const int4* mrow = (const int4*)(mask + (size_t)b * J_);
        int s = 0;
#pragma unroll
        for (int i = 0; i < 4; i++) {
            const int4 v = mrow[i * 256 + t];
            s += (v.x > 0) + (v.y > 0) + (v.z > 0) + (v.w > 0);
        }
        float fs = (float)s;
#pragma unroll
        for (int off = 32; off; off >>= 1) fs += __shfl_xor(fs, off);
        if (lane == 0) redc[wid] = fs;
    }
    __syncthreads();
    const float cn = fmaxf((redc[0] + redc[1]) + (redc[2] + redc[3]), 1.f);
    if (t < D_) c_lds[t] = pooled[(size_t)b * D_ + t] / cn;
    __syncthreads();

    // layer 1: 64 -> 256
    float acc = eb1[t];
#pragma unroll
    for (int d = 0; d < D_; d++)
        acc = fmaf(c_lds[d], eW1[(size_t)d * E_ + t], acc);

    float s = acc, s2 = acc * acc;
#pragma unroll
    for (int off = 32; off; off >>= 1) {
        s  += __shfl_xor(s, off);
        s2 += __shfl_xor(s2, off);
    }
    if ((t & 63) == 0) { red[wid * 2] = s; red[wid * 2 + 1] = s2; }
    __syncthreads();
    s  = red[0] + red[2] + red[4] + red[6];
    s2 = red[1] + red[3] + red[5] + red[7];
    const float m = s * (1.f / (float)E_);
    const float v = fmaf(-m, m, s2 * (1.f / (float)E_));
    const float r = rsqrtf(v + 1e-5f);
    e_lds[t] = fmaxf(0.f, (acc - m) * r);
    __syncthreads();

    // layer 2: 256 -> 64, first wave only
    if (t < 64) {
        float a2 = eb2[t];
#pragma unroll 8
        for (int k = 0; k < E_; k++)
            a2 = fmaf(e_lds[k], eW2[(size_t)k * 64 + t], a2);

        float u = a2, u2 = a2 * a2;
#pragma unroll
        for (int off = 32; off; off >>= 1) {
            u  += __shfl_xor(u, off);
            u2 += __shfl_xor(u2, off);
        }
        const float m2 = u * (1.f / 64.f);
        const float v2 = fmaf(-m2, m2, u2 * (1.f / 64.f));
        const float r2 = rsqrtf(v2 + 1e-5f);
        const float o  = fmaxf(0.f, (a2 - m2) * r2);
        if (t < Z_) out[(size_t)b * Z_ + t] = o;
        else        out[(size_t)B_ * Z_ + (size_t)b * Z_ + (t - Z_)] = o;
    }
}

// ---------------------------------------------------------------------------
extern "C" void kernel_launch(void* const* d_in, const int* in_sizes, int n_in,
                              void* d_out, int out_size, void* d_ws, size_t ws_size,
                              hipStream_t stream) {
    const float* x    = (const float*)d_in[0];
    const int*   mask = (const int*)d_in[1];
    const float* F    = (const float*)d_in[2];
    const float* hW1  = (const float*)d_in[3];
    const float* hb1  = (const float*)d_in[4];
    const float* hg1  = (const float*)d_in[5];
    const float* hbt1 = (const float*)d_in[6];
    const float* hW2  = (const float*)d_in[7];
    const float* hb2  = (const float*)d_in[8];
    const float* hg2  = (const float*)d_in[9];
    const float* hbt2 = (const float*)d_in[10];
    const float* eW1  = (const float*)d_in[11];
    const float* eb1  = (const float*)d_in[12];
    const float* eW2  = (const float*)d_in[13];
    const float* eb2  = (const float*)d_in[14];
    float* out = (float*)d_out;

    char* ws = (char*)d_ws;
    float*  Gp     = (float*)(ws + OFF_G);
    float4* Gstats = (float4*)(ws + OFF_GSTATS);
    float*  scal   = (float*)(ws + OFF_SCAL);
    float*  w0c    = (float*)(ws + OFF_W0C);
    float*  c3     = (float*)(ws + OFF_C3);
    uint4*  w2f    = (uint4*)(ws + OFF_W2F);
    float*  pooled = (float*)(ws + OFF_POOL);

    pre_kernel<<<1033, 128, 0, stream>>>(F, hW1, hb1, hg1, hbt1, hW2,
                                         Gp, Gstats, scal, w0c, c3, w2f,
                                         (float4*)pooled);
    main_kernel<<<dim3(J_ / (16 * 4 * TPW), B_ / BB), 256, 0, stream>>>(
        x, mask, Gp, Gstats, scal, w0c, c3, w2f, hb2, hg2, hbt2, pooled);
    final_kernel<<<B_, E_, 0, stream>>>(pooled, mask, eW1, eb1, eW2, eb2, out);
}